// Round 3
// baseline (290.706 us; speedup 1.0000x reference)
//
#include <hip/hip_runtime.h>
#include <hip/hip_bf16.h>

// Problem constants (B=2, C=128, H=W=56)
#define BATCH 2
#define CH    128
#define HH    56
#define WW    56
#define HWS   3136        // H*W
#define NPOS  6272        // B*H*W
#define HEADS 4
#define HD    32

// ---------------------------------------------------------------------------
// LN1: x (NCHW) -> xn (N x C, NHWC)
// ---------------------------------------------------------------------------
__global__ __launch_bounds__(256) void ln1_kernel(const float* __restrict__ x,
                                                  const float* __restrict__ g,
                                                  const float* __restrict__ be,
                                                  float* __restrict__ out) {
  __shared__ float tile[128 * 65];
  __shared__ float mu_s[64];
  __shared__ float rs_s[64];
  const int p0 = blockIdx.x * 64;
  const int b  = (p0 >= HWS) ? 1 : 0;
  const int s0 = p0 - b * HWS;
  const int tid = threadIdx.x;

  for (int idx = tid; idx < 8192; idx += 256) {
    int c = idx >> 6, p = idx & 63;
    tile[c * 65 + p] = x[(size_t)(b * CH + c) * HWS + s0 + p];
  }
  __syncthreads();
  {
    int p = tid >> 2, q = tid & 3;
    float sum = 0.f, sq = 0.f;
#pragma unroll
    for (int t = 0; t < 32; ++t) {
      float v = tile[(q * 32 + t) * 65 + p];
      sum += v; sq += v * v;
    }
    sum += __shfl_xor(sum, 1); sq += __shfl_xor(sq, 1);
    sum += __shfl_xor(sum, 2); sq += __shfl_xor(sq, 2);
    float mu  = sum * 0.0078125f;
    float var = sq * 0.0078125f - mu * mu;
    float rs  = rsqrtf(var + 1e-5f);
    if (q == 0) { mu_s[p] = mu; rs_s[p] = rs; }
  }
  __syncthreads();
  for (int idx = tid; idx < 8192; idx += 256) {
    int nl = idx >> 7, c = idx & 127;
    float v = (tile[c * 65 + nl] - mu_s[nl]) * rs_s[nl] * g[c] + be[c];
    out[(size_t)(p0 + nl) * CH + c] = v;
  }
}

// ---------------------------------------------------------------------------
// LN2: x2 (N x C) -> xn2 (N x C).  One 32-lane group per position.
// ---------------------------------------------------------------------------
__global__ __launch_bounds__(256) void ln2_kernel(const float* __restrict__ xin,
                                                  const float* __restrict__ g,
                                                  const float* __restrict__ be,
                                                  float* __restrict__ out) {
  const int tid  = threadIdx.x;
  const int grp  = tid >> 5;
  const int lane = tid & 31;
  const int n = blockIdx.x * 8 + grp;
  const float4* row = reinterpret_cast<const float4*>(xin + (size_t)n * CH);
  float4 v = row[lane];
  float sum = v.x + v.y + v.z + v.w;
  float sq  = v.x * v.x + v.y * v.y + v.z * v.z + v.w * v.w;
#pragma unroll
  for (int o = 1; o < 32; o <<= 1) {
    sum += __shfl_xor(sum, o, 32);
    sq  += __shfl_xor(sq, o, 32);
  }
  float mu = sum * 0.0078125f;
  float rs = rsqrtf(sq * 0.0078125f - mu * mu + 1e-5f);
  float4 gg = reinterpret_cast<const float4*>(g)[lane];
  float4 bb = reinterpret_cast<const float4*>(be)[lane];
  float4 o4;
  o4.x = (v.x - mu) * rs * gg.x + bb.x;
  o4.y = (v.y - mu) * rs * gg.y + bb.y;
  o4.z = (v.z - mu) * rs * gg.z + bb.z;
  o4.w = (v.w - mu) * rs * gg.w + bb.w;
  reinterpret_cast<float4*>(out + (size_t)n * CH)[lane] = o4;
}

// ---------------------------------------------------------------------------
// Shared GEMM chunk: stages a 64-row x 64-k tile of A and W (transposed,
// XOR-swizzled so compute-phase float4 LDS reads are conflict-free),
// accumulates 4x4 per thread.  256 threads, tx=tid&15 (cols), ty=tid>>4 (rows).
// ---------------------------------------------------------------------------
__device__ __forceinline__ void gemm_chunk(const float* __restrict__ A,
                                           const float* __restrict__ Wt,
                                           int strideA, int strideW, int kc,
                                           int p0, int n0, int tx, int ty, int tid,
                                           float (&acc)[4][4],
                                           float* __restrict__ As,
                                           float* __restrict__ Ws) {
  for (int idx = tid; idx < 4096; idx += 256) {
    int c = idx & 63, m = idx >> 6;
    int col = ((((m >> 2) ^ (c & 15)) << 2) | (m & 3));
    As[c * 64 + col] = A[(size_t)(p0 + m) * strideA + kc + c];
    Ws[c * 64 + col] = Wt[(size_t)(n0 + m) * strideW + kc + c];
  }
  __syncthreads();
#pragma unroll 8
  for (int k = 0; k < 64; ++k) {
    float4 a = *reinterpret_cast<const float4*>(&As[k * 64 + ((ty ^ (k & 15)) << 2)]);
    float4 b = *reinterpret_cast<const float4*>(&Ws[k * 64 + ((tx ^ (k & 15)) << 2)]);
    float ar[4] = {a.x, a.y, a.z, a.w};
    float br[4] = {b.x, b.y, b.z, b.w};
#pragma unroll
    for (int r = 0; r < 4; ++r)
#pragma unroll
      for (int s = 0; s < 4; ++s)
        acc[r][s] = fmaf(ar[r], br[s], acc[r][s]);
  }
}

__device__ __forceinline__ float gelu_exact(float v) {
  return 0.5f * v * (1.0f + erff(v * 0.70710678118654752f));
}

// out[n][kout] = act(A @ W^T + bias);  A: N x K, W: Kout x K, out: N x Kout
template <bool GELU>
__global__ __launch_bounds__(256) void gemm_bias_act(const float* __restrict__ A,
                                                     const float* __restrict__ Wt,
                                                     const float* __restrict__ bias,
                                                     float* __restrict__ out,
                                                     int K, int Kout) {
  __shared__ float As[64 * 64];
  __shared__ float Ws[64 * 64];
  const int tid = threadIdx.x;
  const int tx = tid & 15, ty = tid >> 4;
  const int p0 = blockIdx.x * 64;
  const int n0 = blockIdx.y * 64;
  float acc[4][4] = {};
  for (int kc = 0; kc < K; kc += 64) {
    if (kc) __syncthreads();
    gemm_chunk(A, Wt, K, K, kc, p0, n0, tx, ty, tid, acc, As, Ws);
  }
  float4 bv = *reinterpret_cast<const float4*>(&bias[n0 + tx * 4]);
  float br[4] = {bv.x, bv.y, bv.z, bv.w};
#pragma unroll
  for (int r = 0; r < 4; ++r) {
    float4 o;
    o.x = acc[r][0] + br[0];
    o.y = acc[r][1] + br[1];
    o.z = acc[r][2] + br[2];
    o.w = acc[r][3] + br[3];
    if (GELU) {
      o.x = gelu_exact(o.x); o.y = gelu_exact(o.y);
      o.z = gelu_exact(o.z); o.w = gelu_exact(o.w);
    }
    *reinterpret_cast<float4*>(&out[(size_t)(p0 + ty * 4 + r) * Kout + n0 + tx * 4]) = o;
  }
}

// x2 = x_nchw + A1@W1^T + b1 + A2@W2^T + b2   (out NHWC)
__global__ __launch_bounds__(256) void proj_kernel(const float* __restrict__ A1,
                                                   const float* __restrict__ W1,
                                                   const float* __restrict__ b1,
                                                   const float* __restrict__ A2,
                                                   const float* __restrict__ W2,
                                                   const float* __restrict__ b2,
                                                   const float* __restrict__ xres,
                                                   float* __restrict__ x2out) {
  __shared__ float As[64 * 64];
  __shared__ float Ws[64 * 64];
  const int tid = threadIdx.x;
  const int tx = tid & 15, ty = tid >> 4;
  const int p0 = blockIdx.x * 64;
  const int n0 = blockIdx.y * 64;
  const int b  = (p0 >= HWS) ? 1 : 0;
  const int s0 = p0 - b * HWS;
  float acc[4][4] = {};
  for (int cc = 0; cc < 4; ++cc) {
    const float* A  = (cc < 2) ? A1 : A2;
    const float* Wm = (cc < 2) ? W1 : W2;
    int kc = (cc & 1) * 64;
    if (cc) __syncthreads();
    gemm_chunk(A, Wm, CH, CH, kc, p0, n0, tx, ty, tid, acc, As, Ws);
  }
  float4 bv1 = *reinterpret_cast<const float4*>(&b1[n0 + tx * 4]);
  float4 bv2 = *reinterpret_cast<const float4*>(&b2[n0 + tx * 4]);
  float bsum[4] = {bv1.x + bv2.x, bv1.y + bv2.y, bv1.z + bv2.z, bv1.w + bv2.w};
  float res[4][4];
#pragma unroll
  for (int s = 0; s < 4; ++s) {
    int col = n0 + tx * 4 + s;
    float4 xr = *reinterpret_cast<const float4*>(
        &xres[(size_t)(b * CH + col) * HWS + s0 + ty * 4]);
    res[0][s] = acc[0][s] + bsum[s] + xr.x;
    res[1][s] = acc[1][s] + bsum[s] + xr.y;
    res[2][s] = acc[2][s] + bsum[s] + xr.z;
    res[3][s] = acc[3][s] + bsum[s] + xr.w;
  }
#pragma unroll
  for (int r = 0; r < 4; ++r) {
    float4 o = make_float4(res[r][0], res[r][1], res[r][2], res[r][3]);
    *reinterpret_cast<float4*>(&x2out[(size_t)(p0 + ty * 4 + r) * CH + n0 + tx * 4]) = o;
  }
}

// d_out (NCHW) = x2 (NHWC) + h @ fc2_w^T + fc2_b ; K = 256
__global__ __launch_bounds__(256) void fc2_kernel(const float* __restrict__ A,
                                                  const float* __restrict__ Wt,
                                                  const float* __restrict__ bias,
                                                  const float* __restrict__ x2,
                                                  float* __restrict__ out) {
  __shared__ float As[64 * 64];
  __shared__ float Ws[64 * 64];
  const int tid = threadIdx.x;
  const int tx = tid & 15, ty = tid >> 4;
  const int p0 = blockIdx.x * 64;
  const int n0 = blockIdx.y * 64;
  const int b  = (p0 >= HWS) ? 1 : 0;
  const int s0 = p0 - b * HWS;
  float acc[4][4] = {};
  for (int kc = 0; kc < 256; kc += 64) {
    if (kc) __syncthreads();
    gemm_chunk(A, Wt, 256, 256, kc, p0, n0, tx, ty, tid, acc, As, Ws);
  }
  float4 bv = *reinterpret_cast<const float4*>(&bias[n0 + tx * 4]);
  float res[4][4];
#pragma unroll
  for (int r = 0; r < 4; ++r) {
    float4 xv = *reinterpret_cast<const float4*>(
        &x2[(size_t)(p0 + ty * 4 + r) * CH + n0 + tx * 4]);
    res[r][0] = acc[r][0] + bv.x + xv.x;
    res[r][1] = acc[r][1] + bv.y + xv.y;
    res[r][2] = acc[r][2] + bv.z + xv.z;
    res[r][3] = acc[r][3] + bv.w + xv.w;
  }
#pragma unroll
  for (int s = 0; s < 4; ++s) {
    int col = n0 + tx * 4 + s;
    float4 o = make_float4(res[0][s], res[1][s], res[2][s], res[3][s]);
    *reinterpret_cast<float4*>(&out[(size_t)(b * CH + col) * HWS + s0 + ty * 4]) = o;
  }
}

// ---------------------------------------------------------------------------
// Neighborhood attention.  qkv: N x 384 (q:0..127, k:128..255, v:256..383,
// head h occupies [h*32, h*32+32)).  One thread per (b, h, i, j).
// ---------------------------------------------------------------------------
template <int NW>
__global__ __launch_bounds__(64) void natten_kernel(const float* __restrict__ qkv,
                                                    const float* __restrict__ rpb,
                                                    float* __restrict__ out) {
  const int i  = blockIdx.x;
  const int bh = blockIdx.y;
  const int b  = bh >> 2;
  const int h  = bh & 3;
  const int j  = threadIdx.x;
  if (j >= WW) return;
  const int n = b * HWS + i * WW + j;

  const float scale = 0.17677669529663687f;  // 1/sqrt(32)
  float4 q[8];
  const float4* qp = reinterpret_cast<const float4*>(qkv + (size_t)n * 384 + h * 32);
#pragma unroll
  for (int t = 0; t < 8; ++t) {
    q[t] = qp[t];
    q[t].x *= scale; q[t].y *= scale; q[t].z *= scale; q[t].w *= scale;
  }
  const int si = min(max(i - NW / 2, 0), HH - NW);
  const int sj = min(max(j - NW / 2, 0), WW - NW);
  // bias(ki,kj) = rpb[h][NW-1 + ki - (i-si)][NW-1 + kj - (j-sj)]
  const float* rb = rpb + h * (2 * NW - 1) * (2 * NW - 1)
                    + (NW - 1 - (i - si)) * (2 * NW - 1) + (NW - 1 - (j - sj));
  float sc[NW * NW];
  float mx = -1e30f;
#pragma unroll
  for (int ki = 0; ki < NW; ++ki) {
#pragma unroll
    for (int kj = 0; kj < NW; ++kj) {
      const int nn = b * HWS + (si + ki) * WW + sj + kj;
      const float4* kp = reinterpret_cast<const float4*>(qkv + (size_t)nn * 384 + 128 + h * 32);
      float a0 = 0.f, a1 = 0.f, a2 = 0.f, a3 = 0.f;
#pragma unroll
      for (int t = 0; t < 8; t += 4) {
        float4 k0 = kp[t], k1 = kp[t + 1], k2 = kp[t + 2], k3 = kp[t + 3];
        a0 += q[t].x * k0.x + q[t].y * k0.y + q[t].z * k0.z + q[t].w * k0.w;
        a1 += q[t + 1].x * k1.x + q[t + 1].y * k1.y + q[t + 1].z * k1.z + q[t + 1].w * k1.w;
        a2 += q[t + 2].x * k2.x + q[t + 2].y * k2.y + q[t + 2].z * k2.z + q[t + 2].w * k2.w;
        a3 += q[t + 3].x * k3.x + q[t + 3].y * k3.y + q[t + 3].z * k3.z + q[t + 3].w * k3.w;
      }
      float d = (a0 + a1) + (a2 + a3) + rb[ki * (2 * NW - 1) + kj];
      sc[ki * NW + kj] = d;
      mx = fmaxf(mx, d);
    }
  }
  float ssum = 0.f;
#pragma unroll
  for (int kk = 0; kk < NW * NW; ++kk) {
    sc[kk] = __expf(sc[kk] - mx);
    ssum += sc[kk];
  }
  float4 o[8];
#pragma unroll
  for (int t = 0; t < 8; ++t) o[t] = make_float4(0.f, 0.f, 0.f, 0.f);
#pragma unroll
  for (int ki = 0; ki < NW; ++ki) {
#pragma unroll
    for (int kj = 0; kj < NW; ++kj) {
      const int nn = b * HWS + (si + ki) * WW + sj + kj;
      const float4* vp = reinterpret_cast<const float4*>(qkv + (size_t)nn * 384 + 256 + h * 32);
      float p = sc[ki * NW + kj];
#pragma unroll
      for (int t = 0; t < 8; ++t) {
        float4 vv = vp[t];
        o[t].x = fmaf(p, vv.x, o[t].x);
        o[t].y = fmaf(p, vv.y, o[t].y);
        o[t].z = fmaf(p, vv.z, o[t].z);
        o[t].w = fmaf(p, vv.w, o[t].w);
      }
    }
  }
  float inv = 1.0f / ssum;
  float4* op = reinterpret_cast<float4*>(out + (size_t)n * CH + h * 32);
#pragma unroll
  for (int t = 0; t < 8; ++t) {
    op[t] = make_float4(o[t].x * inv, o[t].y * inv, o[t].z * inv, o[t].w * inv);
  }
}

// ---------------------------------------------------------------------------
extern "C" void kernel_launch(void* const* d_in, const int* in_sizes, int n_in,
                              void* d_out, int out_size, void* d_ws, size_t ws_size,
                              hipStream_t stream) {
  const float* x       = (const float*)d_in[0];
  const float* ln1_g   = (const float*)d_in[1];
  const float* ln1_b   = (const float*)d_in[2];
  const float* qkv_w1  = (const float*)d_in[3];
  const float* qkv_b1  = (const float*)d_in[4];
  const float* proj_w1 = (const float*)d_in[5];
  const float* proj_b1 = (const float*)d_in[6];
  const float* rpb1    = (const float*)d_in[7];
  const float* qkv_w2  = (const float*)d_in[8];
  const float* qkv_b2  = (const float*)d_in[9];
  const float* proj_w2 = (const float*)d_in[10];
  const float* proj_b2 = (const float*)d_in[11];
  const float* rpb2    = (const float*)d_in[12];
  const float* ln2_g   = (const float*)d_in[13];
  const float* ln2_b   = (const float*)d_in[14];
  const float* fc1_w   = (const float*)d_in[15];
  const float* fc1_b   = (const float*)d_in[16];
  const float* fc2_w   = (const float*)d_in[17];
  const float* fc2_b   = (const float*)d_in[18];
  float* out = (float*)d_out;

  float* ws    = (float*)d_ws;
  float* xn    = ws;                       // N*128
  float* qkv1  = xn + (size_t)NPOS * 128;  // N*384
  float* qkv2  = qkv1 + (size_t)NPOS * 384;
  float* attn1 = qkv2 + (size_t)NPOS * 384;  // N*128
  float* attn2 = attn1 + (size_t)NPOS * 128;
  float* x2    = attn2 + (size_t)NPOS * 128;
  float* xn2   = x2 + (size_t)NPOS * 128;
  float* hbuf  = xn2 + (size_t)NPOS * 128;  // N*256

  ln1_kernel<<<98, 256, 0, stream>>>(x, ln1_g, ln1_b, xn);
  gemm_bias_act<false><<<dim3(98, 6), 256, 0, stream>>>(xn, qkv_w1, qkv_b1, qkv1, 128, 384);
  gemm_bias_act<false><<<dim3(98, 6), 256, 0, stream>>>(xn, qkv_w2, qkv_b2, qkv2, 128, 384);
  natten_kernel<7><<<dim3(HH, BATCH * HEADS), 64, 0, stream>>>(qkv1, rpb1, attn1);
  natten_kernel<5><<<dim3(HH, BATCH * HEADS), 64, 0, stream>>>(qkv2, rpb2, attn2);
  proj_kernel<<<dim3(98, 2), 256, 0, stream>>>(attn1, proj_w1, proj_b1,
                                               attn2, proj_w2, proj_b2, x, x2);
  ln2_kernel<<<784, 256, 0, stream>>>(x2, ln2_g, ln2_b, xn2);
  gemm_bias_act<true><<<dim3(98, 4), 256, 0, stream>>>(xn2, fc1_w, fc1_b, hbuf, 128, 256);
  fc2_kernel<<<dim3(98, 2), 256, 0, stream>>>(hbuf, fc2_w, fc2_b, x2, out);
}

// Round 4
// 157.846 us; speedup vs baseline: 1.8417x; 1.8417x over previous
//
#include <hip/hip_runtime.h>
#include <hip/hip_bf16.h>

// Problem constants (B=2, C=128, H=W=56)
#define BATCH 2
#define CH    128
#define HH    56
#define WW    56
#define HWS   3136        // H*W
#define NPOS  6272        // B*H*W
#define HEADS 4
#define HD    32

using f32x4 = __attribute__((ext_vector_type(4))) float;
using s16x8 = __attribute__((ext_vector_type(8))) short;

// fp32 -> bf16 round-to-nearest-even (manual, header-version-proof)
__device__ __forceinline__ unsigned short f2bf(float f) {
  unsigned u = __builtin_bit_cast(unsigned, f);
  u += 0x7FFFu + ((u >> 16) & 1u);
  return (unsigned short)(u >> 16);
}
__device__ __forceinline__ unsigned pack2bf(float a, float b) {
  return (unsigned)f2bf(a) | ((unsigned)f2bf(b) << 16);
}

// ---------------------------------------------------------------------------
// Weight conversion fp32 -> bf16 into ws.  192 blocks x 256 thr x 4 elems.
// segments: qkv_w1(49152) qkv_w2(49152) proj_w1(16384) proj_w2(16384)
//           fc1_w(32768) fc2_w(32768)
// ---------------------------------------------------------------------------
__global__ __launch_bounds__(256) void convert_weights(
    const float* __restrict__ qw1, const float* __restrict__ qw2,
    const float* __restrict__ pw1, const float* __restrict__ pw2,
    const float* __restrict__ f1w, const float* __restrict__ f2w,
    unsigned short* __restrict__ wb) {
  int bid = blockIdx.x;
  const float* src; unsigned short* dst; int base;
  if (bid < 48)       { src = qw1; dst = wb;           base = bid * 1024; }
  else if (bid < 96)  { src = qw2; dst = wb + 49152;   base = (bid - 48) * 1024; }
  else if (bid < 112) { src = pw1; dst = wb + 98304;   base = (bid - 96) * 1024; }
  else if (bid < 128) { src = pw2; dst = wb + 114688;  base = (bid - 112) * 1024; }
  else if (bid < 160) { src = f1w; dst = wb + 131072;  base = (bid - 128) * 1024; }
  else                { src = f2w; dst = wb + 163840;  base = (bid - 160) * 1024; }
  int i = base + threadIdx.x * 4;
  float4 v = *reinterpret_cast<const float4*>(src + i);
  uint2 o;
  o.x = pack2bf(v.x, v.y);
  o.y = pack2bf(v.z, v.w);
  *reinterpret_cast<uint2*>(dst + i) = o;
}

// ---------------------------------------------------------------------------
// LN1: x (NCHW fp32) -> xn (N x C, bf16)
// ---------------------------------------------------------------------------
__global__ __launch_bounds__(256) void ln1_kernel(const float* __restrict__ x,
                                                  const float* __restrict__ g,
                                                  const float* __restrict__ be,
                                                  unsigned short* __restrict__ out) {
  __shared__ float tile[128 * 65];
  __shared__ float mu_s[64];
  __shared__ float rs_s[64];
  const int p0 = blockIdx.x * 64;
  const int b  = (p0 >= HWS) ? 1 : 0;
  const int s0 = p0 - b * HWS;
  const int tid = threadIdx.x;

  for (int idx = tid; idx < 8192; idx += 256) {
    int c = idx >> 6, p = idx & 63;
    tile[c * 65 + p] = x[(size_t)(b * CH + c) * HWS + s0 + p];
  }
  __syncthreads();
  {
    int p = tid >> 2, q = tid & 3;
    float sum = 0.f, sq = 0.f;
#pragma unroll
    for (int t = 0; t < 32; ++t) {
      float v = tile[(q * 32 + t) * 65 + p];
      sum += v; sq += v * v;
    }
    sum += __shfl_xor(sum, 1); sq += __shfl_xor(sq, 1);
    sum += __shfl_xor(sum, 2); sq += __shfl_xor(sq, 2);
    float mu  = sum * 0.0078125f;
    float var = sq * 0.0078125f - mu * mu;
    float rs  = rsqrtf(var + 1e-5f);
    if (q == 0) { mu_s[p] = mu; rs_s[p] = rs; }
  }
  __syncthreads();
  // write bf16 pairs: idx over 64 pos x 64 col-pairs
  for (int idx = tid; idx < 4096; idx += 256) {
    int nl = idx >> 6, c2 = idx & 63;
    int c0 = 2 * c2;
    float v0 = (tile[c0 * 65 + nl] - mu_s[nl]) * rs_s[nl] * g[c0] + be[c0];
    float v1 = (tile[(c0 + 1) * 65 + nl] - mu_s[nl]) * rs_s[nl] * g[c0 + 1] + be[c0 + 1];
    reinterpret_cast<unsigned*>(out)[(size_t)(p0 + nl) * 64 + c2] = pack2bf(v0, v1);
  }
}

// ---------------------------------------------------------------------------
// LN2: x2 (N x C fp32) -> xn2 (N x C bf16).  One 32-lane group per position.
// ---------------------------------------------------------------------------
__global__ __launch_bounds__(256) void ln2_kernel(const float* __restrict__ xin,
                                                  const float* __restrict__ g,
                                                  const float* __restrict__ be,
                                                  unsigned short* __restrict__ out) {
  const int tid  = threadIdx.x;
  const int grp  = tid >> 5;
  const int lane = tid & 31;
  const int n = blockIdx.x * 8 + grp;
  const float4* row = reinterpret_cast<const float4*>(xin + (size_t)n * CH);
  float4 v = row[lane];
  float sum = v.x + v.y + v.z + v.w;
  float sq  = v.x * v.x + v.y * v.y + v.z * v.z + v.w * v.w;
#pragma unroll
  for (int o = 1; o < 32; o <<= 1) {
    sum += __shfl_xor(sum, o, 32);
    sq  += __shfl_xor(sq, o, 32);
  }
  float mu = sum * 0.0078125f;
  float rs = rsqrtf(sq * 0.0078125f - mu * mu + 1e-5f);
  float4 gg = reinterpret_cast<const float4*>(g)[lane];
  float4 bb = reinterpret_cast<const float4*>(be)[lane];
  uint2 o2;
  o2.x = pack2bf((v.x - mu) * rs * gg.x + bb.x, (v.y - mu) * rs * gg.y + bb.y);
  o2.y = pack2bf((v.z - mu) * rs * gg.z + bb.z, (v.w - mu) * rs * gg.w + bb.w);
  reinterpret_cast<uint2*>(out + (size_t)n * CH)[lane] = o2;
}

// ---------------------------------------------------------------------------
// MFMA 64x64 tile machinery.  bf16 inputs, fp32 acc.
// LDS tiles [64 rows][64 k] bf16 with byte ^= (row&7)<<4 XOR swizzle
// (written reg-staged with swizzle, read with same swizzle — rule #21).
// 256 threads = 4 waves; wave w covers quadrant (w>>1, w&1) = 32x32,
// 2x2 fragments of 16x16x32.  C/D layout: col=lane&15, row=(lane>>4)*4+reg.
// ---------------------------------------------------------------------------
__device__ __forceinline__ void mfma_stage(const unsigned short* __restrict__ A,
                                           const unsigned short* __restrict__ W,
                                           int sA, int sW, int p0, int n0, int kc,
                                           int tid, char* AsB, char* WsB) {
#pragma unroll
  for (int c = 0; c < 2; ++c) {
    int lin = c * 256 + tid;          // 0..511
    int row = lin >> 3;               // 0..63
    int k8  = (lin & 7) << 3;         // 0..56
    int byte = (row << 7) + (k8 << 1);
    byte ^= (row & 7) << 4;
    *reinterpret_cast<uint4*>(AsB + byte) =
        *reinterpret_cast<const uint4*>(A + (size_t)(p0 + row) * sA + kc + k8);
    *reinterpret_cast<uint4*>(WsB + byte) =
        *reinterpret_cast<const uint4*>(W + (size_t)(n0 + row) * sW + kc + k8);
  }
}

__device__ __forceinline__ void mfma_compute(int lane, int wr, int wc,
                                             const char* AsB, const char* WsB,
                                             f32x4 (&acc)[2][2]) {
  const int r_lo = lane & 15, kg = lane >> 4;
#pragma unroll
  for (int ks = 0; ks < 2; ++ks) {
    const int koff = ks * 64 + kg * 16;
    s16x8 a[2], bf[2];
#pragma unroll
    for (int fi = 0; fi < 2; ++fi) {
      int row = wr * 32 + fi * 16 + r_lo;
      int byte = (row << 7) + koff; byte ^= (row & 7) << 4;
      a[fi] = *reinterpret_cast<const s16x8*>(AsB + byte);
    }
#pragma unroll
    for (int ci = 0; ci < 2; ++ci) {
      int row = wc * 32 + ci * 16 + r_lo;
      int byte = (row << 7) + koff; byte ^= (row & 7) << 4;
      bf[ci] = *reinterpret_cast<const s16x8*>(WsB + byte);
    }
#pragma unroll
    for (int fi = 0; fi < 2; ++fi)
#pragma unroll
      for (int ci = 0; ci < 2; ++ci)
        acc[fi][ci] = __builtin_amdgcn_mfma_f32_16x16x32_bf16(a[fi], bf[ci], acc[fi][ci], 0, 0, 0);
  }
}

__device__ __forceinline__ float gelu_exact(float v) {
  return 0.5f * v * (1.0f + erff(v * 0.70710678118654752f));
}

// MODE 0: fp32 out = A@W^T + bias (qkv).   MODE 1: bf16 out = gelu(A@W^T+bias) (fc1)
template <int MODE>
__global__ __launch_bounds__(256) void gemm_mfma(const unsigned short* __restrict__ A,
                                                 const unsigned short* __restrict__ W,
                                                 const float* __restrict__ bias,
                                                 void* __restrict__ outv,
                                                 int K, int KOUT) {
  __shared__ char AsB[8192];
  __shared__ char WsB[8192];
  const int tid = threadIdx.x;
  const int lane = tid & 63, w = tid >> 6, wr = w >> 1, wc = w & 1;
  const int p0 = blockIdx.x * 64, n0 = blockIdx.y * 64;
  f32x4 acc[2][2];
#pragma unroll
  for (int i = 0; i < 2; ++i)
#pragma unroll
    for (int j = 0; j < 2; ++j) acc[i][j] = (f32x4){0.f, 0.f, 0.f, 0.f};

  for (int kc = 0; kc < K; kc += 64) {
    if (kc) __syncthreads();
    mfma_stage(A, W, K, K, p0, n0, kc, tid, AsB, WsB);
    __syncthreads();
    mfma_compute(lane, wr, wc, AsB, WsB, acc);
  }
  const int r_lo = lane & 15, kg = lane >> 4;
#pragma unroll
  for (int ci = 0; ci < 2; ++ci) {
    int col = n0 + wc * 32 + ci * 16 + r_lo;
    float bc = bias[col];
#pragma unroll
    for (int fi = 0; fi < 2; ++fi) {
      int row0 = p0 + wr * 32 + fi * 16 + kg * 4;
#pragma unroll
      for (int r = 0; r < 4; ++r) {
        float v = acc[fi][ci][r] + bc;
        if (MODE == 0) {
          reinterpret_cast<float*>(outv)[(size_t)(row0 + r) * KOUT + col] = v;
        } else {
          reinterpret_cast<unsigned short*>(outv)[(size_t)(row0 + r) * KOUT + col] =
              f2bf(gelu_exact(v));
        }
      }
    }
  }
}

// x2 (N x C fp32) = x(NCHW res) + attn1@W1^T + b1 + attn2@W2^T + b2
__global__ __launch_bounds__(256) void proj_mfma(const unsigned short* __restrict__ A1,
                                                 const unsigned short* __restrict__ W1,
                                                 const float* __restrict__ b1,
                                                 const unsigned short* __restrict__ A2,
                                                 const unsigned short* __restrict__ W2,
                                                 const float* __restrict__ b2,
                                                 const float* __restrict__ xres,
                                                 float* __restrict__ x2out) {
  __shared__ char AsB[8192];
  __shared__ char WsB[8192];
  const int tid = threadIdx.x;
  const int lane = tid & 63, w = tid >> 6, wr = w >> 1, wc = w & 1;
  const int p0 = blockIdx.x * 64, n0 = blockIdx.y * 64;
  const int bb = (p0 >= HWS) ? 1 : 0;
  const int s0 = p0 - bb * HWS;
  f32x4 acc[2][2];
#pragma unroll
  for (int i = 0; i < 2; ++i)
#pragma unroll
    for (int j = 0; j < 2; ++j) acc[i][j] = (f32x4){0.f, 0.f, 0.f, 0.f};

  const unsigned short* Ap[2] = {A1, A2};
  const unsigned short* Wp[2] = {W1, W2};
#pragma unroll
  for (int s2 = 0; s2 < 2; ++s2) {
    for (int kc = 0; kc < 128; kc += 64) {
      if (s2 || kc) __syncthreads();
      mfma_stage(Ap[s2], Wp[s2], 128, 128, p0, n0, kc, tid, AsB, WsB);
      __syncthreads();
      mfma_compute(lane, wr, wc, AsB, WsB, acc);
    }
  }
  const int r_lo = lane & 15, kg = lane >> 4;
#pragma unroll
  for (int ci = 0; ci < 2; ++ci) {
    int col = n0 + wc * 32 + ci * 16 + r_lo;
    float bc = b1[col] + b2[col];
#pragma unroll
    for (int fi = 0; fi < 2; ++fi) {
      int rloc = wr * 32 + fi * 16 + kg * 4;
      float4 xr = *reinterpret_cast<const float4*>(
          &xres[(size_t)(bb * CH + col) * HWS + s0 + rloc]);
      int row0 = p0 + rloc;
      x2out[(size_t)(row0 + 0) * CH + col] = acc[fi][ci][0] + bc + xr.x;
      x2out[(size_t)(row0 + 1) * CH + col] = acc[fi][ci][1] + bc + xr.y;
      x2out[(size_t)(row0 + 2) * CH + col] = acc[fi][ci][2] + bc + xr.z;
      x2out[(size_t)(row0 + 3) * CH + col] = acc[fi][ci][3] + bc + xr.w;
    }
  }
}

// d_out (NCHW fp32) = x2 + h @ fc2_w^T + fc2_b ;  K = 256
__global__ __launch_bounds__(256) void fc2_mfma(const unsigned short* __restrict__ A,
                                                const unsigned short* __restrict__ W,
                                                const float* __restrict__ bias,
                                                const float* __restrict__ x2,
                                                float* __restrict__ out) {
  __shared__ char AsB[8192];
  __shared__ char WsB[8192];
  const int tid = threadIdx.x;
  const int lane = tid & 63, w = tid >> 6, wr = w >> 1, wc = w & 1;
  const int p0 = blockIdx.x * 64, n0 = blockIdx.y * 64;
  const int bb = (p0 >= HWS) ? 1 : 0;
  const int s0 = p0 - bb * HWS;
  f32x4 acc[2][2];
#pragma unroll
  for (int i = 0; i < 2; ++i)
#pragma unroll
    for (int j = 0; j < 2; ++j) acc[i][j] = (f32x4){0.f, 0.f, 0.f, 0.f};

  for (int kc = 0; kc < 256; kc += 64) {
    if (kc) __syncthreads();
    mfma_stage(A, W, 256, 256, p0, n0, kc, tid, AsB, WsB);
    __syncthreads();
    mfma_compute(lane, wr, wc, AsB, WsB, acc);
  }
  const int r_lo = lane & 15, kg = lane >> 4;
#pragma unroll
  for (int ci = 0; ci < 2; ++ci) {
    int col = n0 + wc * 32 + ci * 16 + r_lo;
    float bc = bias[col];
#pragma unroll
    for (int fi = 0; fi < 2; ++fi) {
      int rloc = wr * 32 + fi * 16 + kg * 4;
      int row0 = p0 + rloc;
      float4 o;
      o.x = acc[fi][ci][0] + bc + x2[(size_t)(row0 + 0) * CH + col];
      o.y = acc[fi][ci][1] + bc + x2[(size_t)(row0 + 1) * CH + col];
      o.z = acc[fi][ci][2] + bc + x2[(size_t)(row0 + 2) * CH + col];
      o.w = acc[fi][ci][3] + bc + x2[(size_t)(row0 + 3) * CH + col];
      *reinterpret_cast<float4*>(&out[(size_t)(bb * CH + col) * HWS + s0 + rloc]) = o;
    }
  }
}

// ---------------------------------------------------------------------------
// Neighborhood attention, 8 lanes per output (4 dims each).
// qkv fp32: N x 384 (q:0..127, k:128..255, v:256..383; head h at [h*32,h*32+32)).
// out bf16 N x 128.  Block 256 = 32 groups; grid = 25088/32 = 784.
// ---------------------------------------------------------------------------
template <int NW>
__global__ __launch_bounds__(256) void natten_kernel(const float* __restrict__ qkv,
                                                     const float* __restrict__ rpb,
                                                     unsigned short* __restrict__ out) {
  const int tid = threadIdx.x;
  const int g   = blockIdx.x * 32 + (tid >> 3);   // 0..25087  ((b*4+h)*56+i)*56+j
  const int sub = tid & 7;
  const int j  = g % WW;
  const int t1 = g / WW;
  const int i  = t1 % HH;
  const int t2 = t1 / HH;
  const int h  = t2 & 3;
  const int b  = t2 >> 2;
  const int n  = b * HWS + i * WW + j;

  const float scale = 0.17677669529663687f;  // 1/sqrt(32)
  float4 q = *reinterpret_cast<const float4*>(qkv + (size_t)n * 384 + h * 32 + sub * 4);
  q.x *= scale; q.y *= scale; q.z *= scale; q.w *= scale;

  const int si = min(max(i - NW / 2, 0), HH - NW);
  const int sj = min(max(j - NW / 2, 0), WW - NW);
  const float* rb = rpb + h * (2 * NW - 1) * (2 * NW - 1)
                    + (NW - 1 - (i - si)) * (2 * NW - 1) + (NW - 1 - (j - sj));
  float sc[NW * NW];
  float mx = -1e30f;
#pragma unroll
  for (int ki = 0; ki < NW; ++ki) {
#pragma unroll
    for (int kj = 0; kj < NW; ++kj) {
      const int nn = b * HWS + (si + ki) * WW + sj + kj;
      float4 k4 = *reinterpret_cast<const float4*>(qkv + (size_t)nn * 384 + 128 + h * 32 + sub * 4);
      float p = q.x * k4.x + q.y * k4.y + q.z * k4.z + q.w * k4.w;
      p += __shfl_xor(p, 1);
      p += __shfl_xor(p, 2);
      p += __shfl_xor(p, 4);
      p += rb[ki * (2 * NW - 1) + kj];
      sc[ki * NW + kj] = p;
      mx = fmaxf(mx, p);
    }
  }
  float ssum = 0.f;
#pragma unroll
  for (int kk = 0; kk < NW * NW; ++kk) {
    sc[kk] = __expf(sc[kk] - mx);
    ssum += sc[kk];
  }
  float4 o = make_float4(0.f, 0.f, 0.f, 0.f);
#pragma unroll
  for (int ki = 0; ki < NW; ++ki) {
#pragma unroll
    for (int kj = 0; kj < NW; ++kj) {
      const int nn = b * HWS + (si + ki) * WW + sj + kj;
      float4 v4 = *reinterpret_cast<const float4*>(qkv + (size_t)nn * 384 + 256 + h * 32 + sub * 4);
      float p = sc[ki * NW + kj];
      o.x = fmaf(p, v4.x, o.x);
      o.y = fmaf(p, v4.y, o.y);
      o.z = fmaf(p, v4.z, o.z);
      o.w = fmaf(p, v4.w, o.w);
    }
  }
  float inv = 1.0f / ssum;
  uint2 ov;
  ov.x = pack2bf(o.x * inv, o.y * inv);
  ov.y = pack2bf(o.z * inv, o.w * inv);
  *reinterpret_cast<uint2*>(out + (size_t)n * CH + h * 32 + sub * 4) = ov;
}

// ---------------------------------------------------------------------------
extern "C" void kernel_launch(void* const* d_in, const int* in_sizes, int n_in,
                              void* d_out, int out_size, void* d_ws, size_t ws_size,
                              hipStream_t stream) {
  const float* x       = (const float*)d_in[0];
  const float* ln1_g   = (const float*)d_in[1];
  const float* ln1_b   = (const float*)d_in[2];
  const float* qkv_w1  = (const float*)d_in[3];
  const float* qkv_b1  = (const float*)d_in[4];
  const float* proj_w1 = (const float*)d_in[5];
  const float* proj_b1 = (const float*)d_in[6];
  const float* rpb1    = (const float*)d_in[7];
  const float* qkv_w2  = (const float*)d_in[8];
  const float* qkv_b2  = (const float*)d_in[9];
  const float* proj_w2 = (const float*)d_in[10];
  const float* proj_b2 = (const float*)d_in[11];
  const float* rpb2    = (const float*)d_in[12];
  const float* ln2_g   = (const float*)d_in[13];
  const float* ln2_b   = (const float*)d_in[14];
  const float* fc1_w   = (const float*)d_in[15];
  const float* fc1_b   = (const float*)d_in[16];
  const float* fc2_w   = (const float*)d_in[17];
  const float* fc2_b   = (const float*)d_in[18];
  float* out = (float*)d_out;

  // workspace carve-up (all offsets 256B-aligned)
  char* wsb = (char*)d_ws;
  unsigned short* xn    = (unsigned short*)(wsb);                    // N*128 bf16  (1,605,632 B)
  float*          qkv1  = (float*)(wsb + 1605632);                   // N*384 f32   (9,633,792 B)
  float*          qkv2  = (float*)(wsb + 11239424);                  // N*384 f32
  unsigned short* attn1 = (unsigned short*)(wsb + 20873216);         // N*128 bf16
  unsigned short* attn2 = (unsigned short*)(wsb + 22478848);         // N*128 bf16
  float*          x2    = (float*)(wsb + 24084480);                  // N*128 f32   (3,211,264 B)
  unsigned short* xn2   = (unsigned short*)(wsb + 27295744);         // N*128 bf16
  unsigned short* hbuf  = (unsigned short*)(wsb + 28901376);         // N*256 bf16  (3,211,264 B)
  unsigned short* wbuf  = (unsigned short*)(wsb + 32112640);         // 196608 bf16

  unsigned short* qw1b = wbuf;
  unsigned short* qw2b = wbuf + 49152;
  unsigned short* pw1b = wbuf + 98304;
  unsigned short* pw2b = wbuf + 114688;
  unsigned short* f1wb = wbuf + 131072;
  unsigned short* f2wb = wbuf + 163840;

  convert_weights<<<192, 256, 0, stream>>>(qkv_w1, qkv_w2, proj_w1, proj_w2,
                                           fc1_w, fc2_w, wbuf);
  ln1_kernel<<<98, 256, 0, stream>>>(x, ln1_g, ln1_b, xn);
  gemm_mfma<0><<<dim3(98, 6), 256, 0, stream>>>(xn, qw1b, qkv_b1, qkv1, 128, 384);
  gemm_mfma<0><<<dim3(98, 6), 256, 0, stream>>>(xn, qw2b, qkv_b2, qkv2, 128, 384);
  natten_kernel<7><<<784, 256, 0, stream>>>(qkv1, rpb1, attn1);
  natten_kernel<5><<<784, 256, 0, stream>>>(qkv2, rpb2, attn2);
  proj_mfma<<<dim3(98, 2), 256, 0, stream>>>(attn1, pw1b, proj_b1,
                                             attn2, pw2b, proj_b2, x, x2);
  ln2_kernel<<<784, 256, 0, stream>>>(x2, ln2_g, ln2_b, xn2);
  gemm_mfma<1><<<dim3(98, 4), 256, 0, stream>>>(xn2, f1wb, fc1_b, hbuf, 128, 256);
  fc2_mfma<<<dim3(98, 2), 256, 0, stream>>>(hbuf, f2wb, fc2_b, x2, out);
}

// Round 7
// 156.304 us; speedup vs baseline: 1.8599x; 1.0099x over previous
//
#include <hip/hip_runtime.h>
#include <hip/hip_bf16.h>

// Problem constants (B=2, C=128, H=W=56)
#define BATCH 2
#define CH    128
#define HH    56
#define WW    56
#define HWS   3136        // H*W
#define NPOS  6272        // B*H*W
#define HEADS 4
#define HD    32

using f32x4 = __attribute__((ext_vector_type(4))) float;
using s16x8 = __attribute__((ext_vector_type(8))) short;

// fp32 -> bf16 round-to-nearest-even
__device__ __forceinline__ unsigned short f2bf(float f) {
  unsigned u = __builtin_bit_cast(unsigned, f);
  u += 0x7FFFu + ((u >> 16) & 1u);
  return (unsigned short)(u >> 16);
}
__device__ __forceinline__ unsigned pack2bf(float a, float b) {
  return (unsigned)f2bf(a) | ((unsigned)f2bf(b) << 16);
}
// 4 packed bf16 (uint2) -> float4
__device__ __forceinline__ float4 bf4tof(uint2 u) {
  float4 r;
  r.x = __builtin_bit_cast(float, u.x << 16);
  r.y = __builtin_bit_cast(float, u.x & 0xFFFF0000u);
  r.z = __builtin_bit_cast(float, u.y << 16);
  r.w = __builtin_bit_cast(float, u.y & 0xFFFF0000u);
  return r;
}

// ---------------------------------------------------------------------------
// Weight conversion fp32 -> bf16 into ws.  192 blocks x 256 thr x 4 elems.
// ---------------------------------------------------------------------------
__global__ __launch_bounds__(256) void convert_weights(
    const float* __restrict__ qw1, const float* __restrict__ qw2,
    const float* __restrict__ pw1, const float* __restrict__ pw2,
    const float* __restrict__ f1w, const float* __restrict__ f2w,
    unsigned short* __restrict__ wb) {
  int bid = blockIdx.x;
  const float* src; unsigned short* dst; int base;
  if (bid < 48)       { src = qw1; dst = wb;           base = bid * 1024; }
  else if (bid < 96)  { src = qw2; dst = wb + 49152;   base = (bid - 48) * 1024; }
  else if (bid < 112) { src = pw1; dst = wb + 98304;   base = (bid - 96) * 1024; }
  else if (bid < 128) { src = pw2; dst = wb + 114688;  base = (bid - 112) * 1024; }
  else if (bid < 160) { src = f1w; dst = wb + 131072;  base = (bid - 128) * 1024; }
  else                { src = f2w; dst = wb + 163840;  base = (bid - 160) * 1024; }
  int i = base + threadIdx.x * 4;
  float4 v = *reinterpret_cast<const float4*>(src + i);
  uint2 o;
  o.x = pack2bf(v.x, v.y);
  o.y = pack2bf(v.z, v.w);
  *reinterpret_cast<uint2*>(dst + i) = o;
}

// ---------------------------------------------------------------------------
// LN1: x (NCHW fp32) -> xn (N x C, bf16)
// ---------------------------------------------------------------------------
__global__ __launch_bounds__(256) void ln1_kernel(const float* __restrict__ x,
                                                  const float* __restrict__ g,
                                                  const float* __restrict__ be,
                                                  unsigned short* __restrict__ out) {
  __shared__ float tile[128 * 65];
  __shared__ float mu_s[64];
  __shared__ float rs_s[64];
  const int p0 = blockIdx.x * 64;
  const int b  = (p0 >= HWS) ? 1 : 0;
  const int s0 = p0 - b * HWS;
  const int tid = threadIdx.x;

  for (int idx = tid; idx < 8192; idx += 256) {
    int c = idx >> 6, p = idx & 63;
    tile[c * 65 + p] = x[(size_t)(b * CH + c) * HWS + s0 + p];
  }
  __syncthreads();
  {
    int p = tid >> 2, q = tid & 3;
    float sum = 0.f, sq = 0.f;
#pragma unroll
    for (int t = 0; t < 32; ++t) {
      float v = tile[(q * 32 + t) * 65 + p];
      sum += v; sq += v * v;
    }
    sum += __shfl_xor(sum, 1); sq += __shfl_xor(sq, 1);
    sum += __shfl_xor(sum, 2); sq += __shfl_xor(sq, 2);
    float mu  = sum * 0.0078125f;
    float var = sq * 0.0078125f - mu * mu;
    float rs  = rsqrtf(var + 1e-5f);
    if (q == 0) { mu_s[p] = mu; rs_s[p] = rs; }
  }
  __syncthreads();
  for (int idx = tid; idx < 4096; idx += 256) {
    int nl = idx >> 6, c2 = idx & 63;
    int c0 = 2 * c2;
    float v0 = (tile[c0 * 65 + nl] - mu_s[nl]) * rs_s[nl] * g[c0] + be[c0];
    float v1 = (tile[(c0 + 1) * 65 + nl] - mu_s[nl]) * rs_s[nl] * g[c0 + 1] + be[c0 + 1];
    reinterpret_cast<unsigned*>(out)[(size_t)(p0 + nl) * 64 + c2] = pack2bf(v0, v1);
  }
}

// ---------------------------------------------------------------------------
// MFMA tile helpers.  LDS bf16 tiles, byte ^= (row&7)<<4 XOR swizzle.
// 256 threads = 4 waves; wave w -> quadrant (w>>1, w&1); 2x2 16x16x32 frags.
// C/D layout: col = lane&15, row = (lane>>4)*4 + reg.
// ---------------------------------------------------------------------------
__device__ __forceinline__ void stage64(const unsigned short* __restrict__ src,
                                        int stride, int row0, int kc,
                                        int tid, char* dstB) {
#pragma unroll
  for (int c = 0; c < 2; ++c) {
    int lin = c * 256 + tid;          // 0..511
    int row = lin >> 3;               // 0..63
    int k8  = (lin & 7) << 3;         // 0..56
    int byte = (row << 7) + (k8 << 1);
    byte ^= (row & 7) << 4;
    *reinterpret_cast<uint4*>(dstB + byte) =
        *reinterpret_cast<const uint4*>(src + (size_t)(row0 + row) * stride + kc + k8);
  }
}

// aStrideB: bytes per A-row in LDS; aKoffB: byte offset of this K-chunk in A row
__device__ __forceinline__ void tile_compute(const char* AsB, int aStrideB, int aKoffB,
                                             const char* WsB, int lane, int wr, int wc,
                                             f32x4 (&acc)[2][2]) {
  const int r_lo = lane & 15, kg = lane >> 4;
#pragma unroll
  for (int ks = 0; ks < 2; ++ks) {
    const int koffW = ks * 64 + kg * 16;
    const int koffA = aKoffB + koffW;
    s16x8 a[2], bf[2];
#pragma unroll
    for (int fi = 0; fi < 2; ++fi) {
      int row = wr * 32 + fi * 16 + r_lo;
      int byte = row * aStrideB + koffA; byte ^= (row & 7) << 4;
      a[fi] = *reinterpret_cast<const s16x8*>(AsB + byte);
    }
#pragma unroll
    for (int ci = 0; ci < 2; ++ci) {
      int row = wc * 32 + ci * 16 + r_lo;
      int byte = (row << 7) + koffW; byte ^= (row & 7) << 4;
      bf[ci] = *reinterpret_cast<const s16x8*>(WsB + byte);
    }
#pragma unroll
    for (int fi = 0; fi < 2; ++fi)
#pragma unroll
      for (int ci = 0; ci < 2; ++ci)
        acc[fi][ci] = __builtin_amdgcn_mfma_f32_16x16x32_bf16(a[fi], bf[ci], acc[fi][ci], 0, 0, 0);
  }
}

__device__ __forceinline__ float gelu_exact(float v) {
  return 0.5f * v * (1.0f + erff(v * 0.70710678118654752f));
}

// ---------------------------------------------------------------------------
// Fused qkv GEMM (both attention branches).  A = xn (N x 128 bf16).
// grid (98, 12): y<6 -> set 1 cols y*64; else set 2 cols (y-6)*64.
// out bf16 N x 384.
// ---------------------------------------------------------------------------
__global__ __launch_bounds__(256) void qkv_mfma(const unsigned short* __restrict__ A,
                                                const unsigned short* __restrict__ W1,
                                                const float* __restrict__ b1,
                                                unsigned short* __restrict__ o1,
                                                const unsigned short* __restrict__ W2,
                                                const float* __restrict__ b2,
                                                unsigned short* __restrict__ o2) {
  __shared__ char AsB[8192];
  __shared__ char WsB[8192];
  const int tid = threadIdx.x;
  const int lane = tid & 63, w = tid >> 6, wr = w >> 1, wc = w & 1;
  const int p0 = blockIdx.x * 64;
  const int yy = blockIdx.y;
  const bool first = yy < 6;
  const unsigned short* W = first ? W1 : W2;
  const float* bias = first ? b1 : b2;
  unsigned short* outp = first ? o1 : o2;
  const int n0 = (first ? yy : yy - 6) * 64;

  f32x4 acc[2][2];
#pragma unroll
  for (int i = 0; i < 2; ++i)
#pragma unroll
    for (int j = 0; j < 2; ++j) acc[i][j] = (f32x4){0.f, 0.f, 0.f, 0.f};

  for (int kc = 0; kc < 128; kc += 64) {
    if (kc) __syncthreads();
    stage64(A, 128, p0, kc, tid, AsB);
    stage64(W, 128, n0, kc, tid, WsB);
    __syncthreads();
    tile_compute(AsB, 128, 0, WsB, lane, wr, wc, acc);
  }
  const int r_lo = lane & 15, kg = lane >> 4;
#pragma unroll
  for (int ci = 0; ci < 2; ++ci) {
    int col = n0 + wc * 32 + ci * 16 + r_lo;
    float bc = bias[col];
#pragma unroll
    for (int fi = 0; fi < 2; ++fi) {
      int row0 = p0 + wr * 32 + fi * 16 + kg * 4;
#pragma unroll
      for (int r = 0; r < 4; ++r)
        outp[(size_t)(row0 + r) * 384 + col] = f2bf(acc[fi][ci][r] + bc);
    }
  }
}

// ---------------------------------------------------------------------------
// x2 (N x C fp32) = x(NCHW res) + attn1@W1^T + b1 + attn2@W2^T + b2
// ---------------------------------------------------------------------------
__global__ __launch_bounds__(256) void proj_mfma(const unsigned short* __restrict__ A1,
                                                 const unsigned short* __restrict__ W1,
                                                 const float* __restrict__ b1,
                                                 const unsigned short* __restrict__ A2,
                                                 const unsigned short* __restrict__ W2,
                                                 const float* __restrict__ b2,
                                                 const float* __restrict__ xres,
                                                 float* __restrict__ x2out) {
  __shared__ char AsB[8192];
  __shared__ char WsB[8192];
  const int tid = threadIdx.x;
  const int lane = tid & 63, w = tid >> 6, wr = w >> 1, wc = w & 1;
  const int p0 = blockIdx.x * 64, n0 = blockIdx.y * 64;
  const int bb = (p0 >= HWS) ? 1 : 0;
  const int s0 = p0 - bb * HWS;
  f32x4 acc[2][2];
#pragma unroll
  for (int i = 0; i < 2; ++i)
#pragma unroll
    for (int j = 0; j < 2; ++j) acc[i][j] = (f32x4){0.f, 0.f, 0.f, 0.f};

  const unsigned short* Ap[2] = {A1, A2};
  const unsigned short* Wp[2] = {W1, W2};
#pragma unroll
  for (int s2 = 0; s2 < 2; ++s2) {
    for (int kc = 0; kc < 128; kc += 64) {
      if (s2 || kc) __syncthreads();
      stage64(Ap[s2], 128, p0, kc, tid, AsB);
      stage64(Wp[s2], 128, n0, kc, tid, WsB);
      __syncthreads();
      tile_compute(AsB, 128, 0, WsB, lane, wr, wc, acc);
    }
  }
  const int r_lo = lane & 15, kg = lane >> 4;
#pragma unroll
  for (int ci = 0; ci < 2; ++ci) {
    int col = n0 + wc * 32 + ci * 16 + r_lo;
    float bc = b1[col] + b2[col];
#pragma unroll
    for (int fi = 0; fi < 2; ++fi) {
      int rloc = wr * 32 + fi * 16 + kg * 4;
      float4 xr = *reinterpret_cast<const float4*>(
          &xres[(size_t)(bb * CH + col) * HWS + s0 + rloc]);
      int row0 = p0 + rloc;
      x2out[(size_t)(row0 + 0) * CH + col] = acc[fi][ci][0] + bc + xr.x;
      x2out[(size_t)(row0 + 1) * CH + col] = acc[fi][ci][1] + bc + xr.y;
      x2out[(size_t)(row0 + 2) * CH + col] = acc[fi][ci][2] + bc + xr.z;
      x2out[(size_t)(row0 + 3) * CH + col] = acc[fi][ci][3] + bc + xr.w;
    }
  }
}

// ---------------------------------------------------------------------------
// fc1 with fused LN2: A = LN(x2) computed in-kernel into LDS (bf16, swizzled).
// out = gelu(A @ fc1_w^T + b) bf16, N x 256.  grid (98, 4).
// ---------------------------------------------------------------------------
__global__ __launch_bounds__(256) void fc1ln_mfma(const float* __restrict__ x2,
                                                  const float* __restrict__ g,
                                                  const float* __restrict__ be,
                                                  const unsigned short* __restrict__ W,
                                                  const float* __restrict__ bias,
                                                  unsigned short* __restrict__ out) {
  __shared__ char AsB[16384];   // 64 rows x 128 k bf16 (256 B/row), swizzled
  __shared__ char WsB[8192];
  const int tid = threadIdx.x;
  const int lane = tid & 63, w = tid >> 6, wr = w >> 1, wc = w & 1;
  const int p0 = blockIdx.x * 64, n0 = blockIdx.y * 64;
  // --- LN2 into AsB: 4 threads per row ---
  {
    const int p = tid >> 2, q = tid & 3;
    const float* row = x2 + (size_t)(p0 + p) * CH + q * 32;
    float4 v[8];
    float sum = 0.f, sq = 0.f;
#pragma unroll
    for (int t = 0; t < 8; ++t) {
      v[t] = *reinterpret_cast<const float4*>(row + t * 4);
      sum += v[t].x + v[t].y + v[t].z + v[t].w;
      sq  += v[t].x * v[t].x + v[t].y * v[t].y + v[t].z * v[t].z + v[t].w * v[t].w;
    }
    sum += __shfl_xor(sum, 1); sq += __shfl_xor(sq, 1);
    sum += __shfl_xor(sum, 2); sq += __shfl_xor(sq, 2);
    float mu = sum * 0.0078125f;
    float rs = rsqrtf(sq * 0.0078125f - mu * mu + 1e-5f);
#pragma unroll
    for (int t = 0; t < 8; t += 2) {
      int d0 = q * 32 + t * 4;
      float4 g0 = *reinterpret_cast<const float4*>(g + d0);
      float4 g1 = *reinterpret_cast<const float4*>(g + d0 + 4);
      float4 b0 = *reinterpret_cast<const float4*>(be + d0);
      float4 b1v = *reinterpret_cast<const float4*>(be + d0 + 4);
      uint4 o;
      o.x = pack2bf((v[t].x - mu) * rs * g0.x + b0.x, (v[t].y - mu) * rs * g0.y + b0.y);
      o.y = pack2bf((v[t].z - mu) * rs * g0.z + b0.z, (v[t].w - mu) * rs * g0.w + b0.w);
      o.z = pack2bf((v[t+1].x - mu) * rs * g1.x + b1v.x, (v[t+1].y - mu) * rs * g1.y + b1v.y);
      o.w = pack2bf((v[t+1].z - mu) * rs * g1.z + b1v.z, (v[t+1].w - mu) * rs * g1.w + b1v.w);
      int byte = p * 256 + q * 64 + (t >> 1) * 16;
      byte ^= (p & 7) << 4;
      *reinterpret_cast<uint4*>(AsB + byte) = o;
    }
  }
  f32x4 acc[2][2];
#pragma unroll
  for (int i = 0; i < 2; ++i)
#pragma unroll
    for (int j = 0; j < 2; ++j) acc[i][j] = (f32x4){0.f, 0.f, 0.f, 0.f};

  for (int kc = 0; kc < 128; kc += 64) {
    __syncthreads();                       // covers LN writes (kc=0) / prior reads
    stage64(W, 128, n0, kc, tid, WsB);
    __syncthreads();
    tile_compute(AsB, 256, kc * 2, WsB, lane, wr, wc, acc);
  }
  const int r_lo = lane & 15, kg = lane >> 4;
#pragma unroll
  for (int ci = 0; ci < 2; ++ci) {
    int col = n0 + wc * 32 + ci * 16 + r_lo;
    float bc = bias[col];
#pragma unroll
    for (int fi = 0; fi < 2; ++fi) {
      int row0 = p0 + wr * 32 + fi * 16 + kg * 4;
#pragma unroll
      for (int r = 0; r < 4; ++r)
        out[(size_t)(row0 + r) * 256 + col] = f2bf(gelu_exact(acc[fi][ci][r] + bc));
    }
  }
}

// ---------------------------------------------------------------------------
// d_out (NCHW fp32) = x2 + h @ fc2_w^T + fc2_b ;  K = 256
// ---------------------------------------------------------------------------
__global__ __launch_bounds__(256) void fc2_mfma(const unsigned short* __restrict__ A,
                                                const unsigned short* __restrict__ W,
                                                const float* __restrict__ bias,
                                                const float* __restrict__ x2,
                                                float* __restrict__ out) {
  __shared__ char AsB[8192];
  __shared__ char WsB[8192];
  const int tid = threadIdx.x;
  const int lane = tid & 63, w = tid >> 6, wr = w >> 1, wc = w & 1;
  const int p0 = blockIdx.x * 64, n0 = blockIdx.y * 64;
  const int bb = (p0 >= HWS) ? 1 : 0;
  const int s0 = p0 - bb * HWS;
  f32x4 acc[2][2];
#pragma unroll
  for (int i = 0; i < 2; ++i)
#pragma unroll
    for (int j = 0; j < 2; ++j) acc[i][j] = (f32x4){0.f, 0.f, 0.f, 0.f};

  for (int kc = 0; kc < 256; kc += 64) {
    if (kc) __syncthreads();
    stage64(A, 256, p0, kc, tid, AsB);
    stage64(W, 256, n0, kc, tid, WsB);
    __syncthreads();
    tile_compute(AsB, 128, 0, WsB, lane, wr, wc, acc);
  }
  const int r_lo = lane & 15, kg = lane >> 4;
#pragma unroll
  for (int ci = 0; ci < 2; ++ci) {
    int col = n0 + wc * 32 + ci * 16 + r_lo;
    float bc = bias[col];
#pragma unroll
    for (int fi = 0; fi < 2; ++fi) {
      int rloc = wr * 32 + fi * 16 + kg * 4;
      int row0 = p0 + rloc;
      float4 o;
      o.x = acc[fi][ci][0] + bc + x2[(size_t)(row0 + 0) * CH + col];
      o.y = acc[fi][ci][1] + bc + x2[(size_t)(row0 + 1) * CH + col];
      o.z = acc[fi][ci][2] + bc + x2[(size_t)(row0 + 2) * CH + col];
      o.w = acc[fi][ci][3] + bc + x2[(size_t)(row0 + 3) * CH + col];
      *reinterpret_cast<float4*>(&out[(size_t)(bb * CH + col) * HWS + s0 + rloc]) = o;
    }
  }
}

// ---------------------------------------------------------------------------
// Neighborhood attention (both windows in one launch), 8 lanes per output.
// qkv bf16: N x 384.  out bf16 N x 128.
// ---------------------------------------------------------------------------
template <int NW>
__device__ __forceinline__ void natten_body(const unsigned short* __restrict__ qkvb,
                                            const float* __restrict__ rpb,
                                            unsigned short* __restrict__ out,
                                            int blk, int tid) {
  const int g   = blk * 32 + (tid >> 3);
  const int sub = tid & 7;
  const int j  = g % WW;
  const int t1 = g / WW;
  const int i  = t1 % HH;
  const int t2 = t1 / HH;
  const int h  = t2 & 3;
  const int b  = t2 >> 2;
  const int n  = b * HWS + i * WW + j;

  const float scale = 0.17677669529663687f;  // 1/sqrt(32)
  float4 q = bf4tof(*reinterpret_cast<const uint2*>(qkvb + (size_t)n * 384 + h * 32 + sub * 4));
  q.x *= scale; q.y *= scale; q.z *= scale; q.w *= scale;

  const int si = min(max(i - NW / 2, 0), HH - NW);
  const int sj = min(max(j - NW / 2, 0), WW - NW);
  const float* rb = rpb + h * (2 * NW - 1) * (2 * NW - 1)
                    + (NW - 1 - (i - si)) * (2 * NW - 1) + (NW - 1 - (j - sj));
  float sc[NW * NW];
  float mx = -1e30f;
#pragma unroll
  for (int ki = 0; ki < NW; ++ki) {
#pragma unroll
    for (int kj = 0; kj < NW; ++kj) {
      const int nn = b * HWS + (si + ki) * WW + sj + kj;
      float4 k4 = bf4tof(*reinterpret_cast<const uint2*>(
          qkvb + (size_t)nn * 384 + 128 + h * 32 + sub * 4));
      float p = q.x * k4.x + q.y * k4.y + q.z * k4.z + q.w * k4.w;
      p += __shfl_xor(p, 1);
      p += __shfl_xor(p, 2);
      p += __shfl_xor(p, 4);
      p += rb[ki * (2 * NW - 1) + kj];
      sc[ki * NW + kj] = p;
      mx = fmaxf(mx, p);
    }
  }
  float ssum = 0.f;
#pragma unroll
  for (int kk = 0; kk < NW * NW; ++kk) {
    sc[kk] = __expf(sc[kk] - mx);
    ssum += sc[kk];
  }
  float4 o = make_float4(0.f, 0.f, 0.f, 0.f);
#pragma unroll
  for (int ki = 0; ki < NW; ++ki) {
#pragma unroll
    for (int kj = 0; kj < NW; ++kj) {
      const int nn = b * HWS + (si + ki) * WW + sj + kj;
      float4 v4 = bf4tof(*reinterpret_cast<const uint2*>(
          qkvb + (size_t)nn * 384 + 256 + h * 32 + sub * 4));
      float p = sc[ki * NW + kj];
      o.x = fmaf(p, v4.x, o.x);
      o.y = fmaf(p, v4.y, o.y);
      o.z = fmaf(p, v4.z, o.z);
      o.w = fmaf(p, v4.w, o.w);
    }
  }
  float inv = 1.0f / ssum;
  uint2 ov;
  ov.x = pack2bf(o.x * inv, o.y * inv);
  ov.y = pack2bf(o.z * inv, o.w * inv);
  *reinterpret_cast<uint2*>(out + (size_t)n * CH + h * 32 + sub * 4) = ov;
}

__global__ __launch_bounds__(256) void natten_fused(const unsigned short* __restrict__ qkv1,
                                                    const float* __restrict__ rpb1,
                                                    unsigned short* __restrict__ a1,
                                                    const unsigned short* __restrict__ qkv2,
                                                    const float* __restrict__ rpb2,
                                                    unsigned short* __restrict__ a2) {
  if (blockIdx.x < 784) natten_body<7>(qkv1, rpb1, a1, blockIdx.x, threadIdx.x);
  else                  natten_body<5>(qkv2, rpb2, a2, blockIdx.x - 784, threadIdx.x);
}

// ---------------------------------------------------------------------------
extern "C" void kernel_launch(void* const* d_in, const int* in_sizes, int n_in,
                              void* d_out, int out_size, void* d_ws, size_t ws_size,
                              hipStream_t stream) {
  const float* x       = (const float*)d_in[0];
  const float* ln1_g   = (const float*)d_in[1];
  const float* ln1_b   = (const float*)d_in[2];
  const float* qkv_w1  = (const float*)d_in[3];
  const float* qkv_b1  = (const float*)d_in[4];
  const float* proj_w1 = (const float*)d_in[5];
  const float* proj_b1 = (const float*)d_in[6];
  const float* rpb1    = (const float*)d_in[7];
  const float* qkv_w2  = (const float*)d_in[8];
  const float* qkv_b2  = (const float*)d_in[9];
  const float* proj_w2 = (const float*)d_in[10];
  const float* proj_b2 = (const float*)d_in[11];
  const float* rpb2    = (const float*)d_in[12];
  const float* ln2_g   = (const float*)d_in[13];
  const float* ln2_b   = (const float*)d_in[14];
  const float* fc1_w   = (const float*)d_in[15];
  const float* fc1_b   = (const float*)d_in[16];
  const float* fc2_w   = (const float*)d_in[17];
  const float* fc2_b   = (const float*)d_in[18];
  float* out = (float*)d_out;

  // workspace carve-up (bytes, all 256B-aligned)
  char* wsb = (char*)d_ws;
  unsigned short* xn    = (unsigned short*)(wsb);              // N*128 bf16 (1,605,632)
  unsigned short* qkv1  = (unsigned short*)(wsb + 1605632);    // N*384 bf16 (4,816,896)
  unsigned short* qkv2  = (unsigned short*)(wsb + 6422528);    // N*384 bf16
  unsigned short* attn1 = (unsigned short*)(wsb + 11239424);   // N*128 bf16
  unsigned short* attn2 = (unsigned short*)(wsb + 12845056);   // N*128 bf16
  float*          x2    = (float*)(wsb + 14450688);            // N*128 f32  (3,211,264)
  unsigned short* hbuf  = (unsigned short*)(wsb + 17661952);   // N*256 bf16 (3,211,264)
  unsigned short* wbuf  = (unsigned short*)(wsb + 20873216);   // 196608 bf16

  unsigned short* qw1b = wbuf;
  unsigned short* qw2b = wbuf + 49152;
  unsigned short* pw1b = wbuf + 98304;
  unsigned short* pw2b = wbuf + 114688;
  unsigned short* f1wb = wbuf + 131072;
  unsigned short* f2wb = wbuf + 163840;

  convert_weights<<<192, 256, 0, stream>>>(qkv_w1, qkv_w2, proj_w1, proj_w2,
                                           fc1_w, fc2_w, wbuf);
  ln1_kernel<<<98, 256, 0, stream>>>(x, ln1_g, ln1_b, xn);
  qkv_mfma<<<dim3(98, 12), 256, 0, stream>>>(xn, qw1b, qkv_b1, qkv1, qw2b, qkv_b2, qkv2);
  natten_fused<<<1568, 256, 0, stream>>>(qkv1, rpb1, attn1, qkv2, rpb2, attn2);
  proj_mfma<<<dim3(98, 2), 256, 0, stream>>>(attn1, pw1b, proj_b1,
                                             attn2, pw2b, proj_b2, x, x2);
  fc1ln_mfma<<<dim3(98, 4), 256, 0, stream>>>(x2, ln2_g, ln2_b, f1wb, fc1_b, hbuf);
  fc2_mfma<<<dim3(98, 2), 256, 0, stream>>>(hbuf, f2wb, fc2_b, x2, out);
}